// Round 18
// baseline (557.889 us; speedup 1.0000x reference)
//
#include <hip/hip_runtime.h>

#define Sn 500
#define Dn 10
#define Tn 40
#define FPn 3
#define FTn 512
#define Hn 64
#define G3 192
#define NHn 4

typedef __attribute__((ext_vector_type(8))) short bf8_t;   // 8 x bf16 bits
typedef __attribute__((ext_vector_type(4))) float f4_t;

__device__ __forceinline__ unsigned short f2bf(float f) {
    union { float f; unsigned int u; } v; v.f = f;
    unsigned int r = v.u + 0x7fffu + ((v.u >> 16) & 1u);
    return (unsigned short)(r >> 16);
}
__device__ __forceinline__ float bflo(unsigned int u) {
    union { unsigned int u; float f; } v; v.u = u << 16; return v.f;
}
__device__ __forceinline__ float bfhi(unsigned int u) {
    union { unsigned int u; float f; } v; v.u = u & 0xffff0000u; return v.f;
}
__device__ __forceinline__ unsigned int cvtpk(float lo, float hi) {
    unsigned int r;
    asm("v_cvt_pk_bf16_f32 %0, %1, %2" : "=v"(r) : "v"(lo), "v"(hi));
    return r;
}
__device__ __forceinline__ float sigmoidf_(float x) { return 1.f / (1.f + __expf(-x)); }
__device__ __forceinline__ float tanhf_(float x) {
    x = fminf(15.f, fmaxf(-15.f, x));
    float e = __expf(2.f * x);
    return (e - 1.f) / (e + 1.f);
}
__device__ __forceinline__ float dot8(uint4 wv, f4_t hA, f4_t hB) {
    return bflo(wv.x) * hA[0] + bfhi(wv.x) * hA[1]
         + bflo(wv.y) * hA[2] + bfhi(wv.y) * hA[3]
         + bflo(wv.z) * hB[0] + bfhi(wv.z) * hB[1]
         + bflo(wv.w) * hB[2] + bfhi(wv.w) * hB[3];
}
union bfu { bf8_t v; unsigned int u[4]; };

// ---------------------------------------------------------------------------
// price_gru: price GRU + attention pooling -> xprice. 500 blocks x 64 thr.
// Must complete before k1_mega (bilinear path reads xprice).
// ---------------------------------------------------------------------------
__global__ __launch_bounds__(64, 1) void price_gru(
    const float* __restrict__ price, const float* __restrict__ Wih_p,
    const float* __restrict__ Whh_p, const float* __restrict__ bih_p,
    const float* __restrict__ bhh_p, const float* __restrict__ Wa_p,
    const float* __restrict__ va_p, float* __restrict__ xprice)
{
    __shared__ __align__(16) unsigned char smp[33160];
    unsigned char* whh2 = smp;                    // [192][128B]
    unsigned char* wa2 = smp + 24576;             // [64][128B]
    float* hbuf = (float*)(smp + 32768);          // [68]
    float* priceL = (float*)(smp + 33040);        // [30]

    const int s = blockIdx.x, l = threadIdx.x;
    {
        const float* W3 = Whh_p + (size_t)s * Hn * G3;
        for (int r = 0; r < 192; ++r) {
            int e = l + r * 64, i = e / G3, j = e - i * G3;
            *(unsigned short*)(whh2 + j * 128 + ((2 * i) ^ ((j & 7) << 4))) = f2bf(W3[e]);
        }
        const float* A3 = Wa_p + (size_t)s * Hn * Hn;
        for (int r = 0; r < 64; ++r) {
            int e = l + r * 64, i = e >> 6, k = e & 63;
            *(unsigned short*)(wa2 + k * 128 + ((2 * i) ^ ((k & 7) << 4))) = f2bf(A3[e]);
        }
        if (l < 30) priceL[l] = price[(size_t)s * 30 + l];
        hbuf[l] = 0.f;
        if (l < 4) hbuf[64 + l] = 0.f;
    }
    __builtin_amdgcn_wave_barrier();
    {
        float wp[3][3];
        #pragma unroll
        for (int i = 0; i < 3; ++i)
            #pragma unroll
            for (int g = 0; g < 3; ++g)
                wp[i][g] = Wih_p[(size_t)s * 3 * G3 + i * G3 + g * 64 + l];
        const float bi0 = bih_p[(size_t)s * G3 + l];
        const float bi1 = bih_p[(size_t)s * G3 + 64 + l];
        const float bi2 = bih_p[(size_t)s * G3 + 128 + l];
        const float bh0 = bhh_p[(size_t)s * G3 + l];
        const float bh1 = bhh_p[(size_t)s * G3 + 64 + l];
        const float bh2 = bhh_p[(size_t)s * G3 + 128 + l];
        const float vak = va_p[(size_t)s * Hn + l];
        const int swl = (l & 7) << 4;
        float h3 = 0.f, m3 = -1e30f, den3 = 0.f, av3 = 0.f;
        for (int t = 0; t < Dn; ++t) {
            float x0 = priceL[t * 3], x1 = priceL[t * 3 + 1], x2 = priceL[t * 3 + 2];
            float gg0 = bi0 + x0 * wp[0][0] + x1 * wp[1][0] + x2 * wp[2][0];
            float gg1 = bi1 + x0 * wp[0][1] + x1 * wp[1][1] + x2 * wp[2][1];
            float gg2 = bi2 + x0 * wp[0][2] + x1 * wp[1][2] + x2 * wp[2][2];
            float gh0 = bh0, gh1 = bh1, gh2 = bh2;
            #pragma unroll
            for (int ic = 0; ic < 8; ++ic) {
                const int off = (ic * 16) ^ swl;
                f4_t hA = *(const f4_t*)&hbuf[ic * 8];
                f4_t hB = *(const f4_t*)&hbuf[ic * 8 + 4];
                uint4 w0 = *(const uint4*)(whh2 + l * 128 + off);
                uint4 w1 = *(const uint4*)(whh2 + (l + 64) * 128 + off);
                uint4 w2 = *(const uint4*)(whh2 + (l + 128) * 128 + off);
                gh0 += dot8(w0, hA, hB); gh1 += dot8(w1, hA, hB); gh2 += dot8(w2, hA, hB);
            }
            float r = sigmoidf_(gg0 + gh0);
            float z = sigmoidf_(gg1 + gh1);
            float n = tanhf_(gg2 + r * gh2);
            h3 = (1.f - z) * n + z * h3;
            __builtin_amdgcn_wave_barrier();
            hbuf[l] = h3;
            __builtin_amdgcn_wave_barrier();
            float sk = 0.f;
            #pragma unroll
            for (int ic = 0; ic < 8; ++ic) {
                const int off = (ic * 16) ^ swl;
                uint4 wv = *(const uint4*)(wa2 + l * 128 + off);
                f4_t hA = *(const f4_t*)&hbuf[ic * 8];
                f4_t hB = *(const f4_t*)&hbuf[ic * 8 + 4];
                sk += dot8(wv, hA, hB);
            }
            float term = tanhf_(sk) * vak;
            #pragma unroll
            for (int off = 32; off; off >>= 1) term += __shfl_xor(term, off);
            float mn = fmaxf(m3, term);
            float s0 = __expf(m3 - mn);
            float p = __expf(term - mn);
            den3 = den3 * s0 + p;
            av3 = av3 * s0 + p * h3;
            m3 = mn;
        }
        xprice[(size_t)s * Hn + l] = av3 / den3;
    }
}

// ---------------------------------------------------------------------------
// k1_mega: 4500 blocks, 9 per stock (XCD-bijective swizzle groups a stock's
// blocks on one XCD so Wih stays L2-hot):
//   sub 0..4 -> gi GEMM fifth (80 rows), BK=32, ALL-coalesced A+B LDS staging,
//               issue-early/write-late.
//   sub 5..8 -> bilinear quarter: u[s][k][i] = sum_j Wb[s,k,i,j]*xprice[j].
//               g-loop UNROLLED x8 with batched loads: 8 loads in flight per
//               wave (r17 proved x4 = -26us; push the same lever further).
// ---------------------------------------------------------------------------
__global__ __launch_bounds__(256) void k1_mega(
    const float* __restrict__ text, const float* __restrict__ Wih,
    const float* __restrict__ bih, float* __restrict__ gi2,
    const float* __restrict__ Wb, const float* __restrict__ xprice,
    float* __restrict__ u)
{
    __shared__ __align__(16) unsigned char sm[18688];

    const int bid = blockIdx.x, tid = threadIdx.x;
    const int xcd = bid & 7, ix = bid >> 3;
    // bijective XCD swizzle, nwg=4500: q=562, r=4
    const int swz = (xcd < 4 ? xcd * 563 : 2252 + (xcd - 4) * 562) + ix;
    const int grp = swz / 9, sub = swz - grp * 9;
    const int w = tid >> 6, l = tid & 63;

    if (sub < 5) {
        // ================= gi GEMM =================
        const int s = grp, fi = sub;
        const int lr = l & 15, kg = l >> 4;
        unsigned short* Asb = (unsigned short*)sm;            // [80][40] bf16
        unsigned char*  Bsb = sm + 6400;                      // 4 x [192][16B]

        const float* xbase = text + ((size_t)s * 400 + fi * 80) * FTn;
        const float* Wihs  = Wih + (size_t)s * FTn * G3;

        f4_t acc[5][3];
        #pragma unroll
        for (int a = 0; a < 5; a++)
            #pragma unroll
            for (int b = 0; b < 3; b++) acc[a][b] = (f4_t){0.f, 0.f, 0.f, 0.f};

        f4_t pa[3];            // A staging: 640 tasks (row,chunk)
        f4_t pb0[3], pb1[3];   // B staging: 768 tasks (kpair, colquad)

        auto aload = [&](int kk) {
            #pragma unroll
            for (int q = 0; q < 3; ++q) {
                int t = tid + q * 256;
                if (q < 2 || tid < 128) {
                    int row = t >> 3, ch = t & 7;
                    pa[q] = *(const f4_t*)(xbase + (size_t)row * FTn + kk * 32 + ch * 4);
                }
            }
        };
        auto bload = [&](int kk) {
            #pragma unroll
            for (int q = 0; q < 3; ++q) {
                int t = tid + q * 256;
                int kp = t / 48, cq = t % 48;
                const float* p = Wihs + (size_t)(kk * 32 + 2 * kp) * G3 + cq * 4;
                pb0[q] = *(const f4_t*)p;
                pb1[q] = *(const f4_t*)(p + G3);
            }
        };
        auto awrite = [&]() {
            #pragma unroll
            for (int q = 0; q < 3; ++q) {
                int t = tid + q * 256;
                if (q < 2 || tid < 128) {
                    int row = t >> 3, ch = t & 7;
                    uint2 uu = { cvtpk(pa[q][0], pa[q][1]), cvtpk(pa[q][2], pa[q][3]) };
                    *(uint2*)((unsigned char*)Asb + row * 80 + ch * 8) = uu;
                }
            }
        };
        auto bwrite = [&]() {
            #pragma unroll
            for (int q = 0; q < 3; ++q) {
                int t = tid + q * 256;
                int kp = t / 48, cq = t % 48;
                int base = (kp >> 2) * 3072 + (kp & 3) * 4;
                #pragma unroll
                for (int i = 0; i < 4; ++i) {
                    int col = cq * 4 + i;
                    int colp = col ^ ((col >> 2) & 7);     // bijective bank swizzle
                    *(unsigned int*)(Bsb + base + colp * 16) = cvtpk(pb0[q][i], pb1[q][i]);
                }
            }
        };

        aload(0); bload(0);
        for (int kk = 0; kk < 16; ++kk) {
            awrite(); bwrite();
            __syncthreads();
            if (kk < 15) { aload(kk + 1); bload(kk + 1); }   // issue-early (T14)
            bf8_t bfr[3];
            #pragma unroll
            for (int nc = 0; nc < 3; ++nc) {
                int col = w * 48 + nc * 16 + lr;
                int colp = col ^ ((col >> 2) & 7);
                bfr[nc] = *(const bf8_t*)(Bsb + kg * 3072 + colp * 16);
            }
            #pragma unroll
            for (int mt = 0; mt < 5; ++mt) {
                bf8_t af = *(const bf8_t*)((unsigned char*)Asb + (mt * 16 + lr) * 80 + kg * 16);
                acc[mt][0] = __builtin_amdgcn_mfma_f32_16x16x32_bf16(af, bfr[0], acc[mt][0], 0, 0, 0);
                acc[mt][1] = __builtin_amdgcn_mfma_f32_16x16x32_bf16(af, bfr[1], acc[mt][1], 0, 0, 0);
                acc[mt][2] = __builtin_amdgcn_mfma_f32_16x16x32_bf16(af, bfr[2], acc[mt][2], 0, 0, 0);
            }
            __syncthreads();
        }

        const float* bihs = bih + (size_t)s * G3 + w * 48 + lr;
        #pragma unroll
        for (int nc = 0; nc < 3; ++nc) {
            const int col = w * 48 + nc * 16 + lr;
            const float bv = bihs[nc * 16];
            #pragma unroll
            for (int mt = 0; mt < 5; ++mt)
                #pragma unroll
                for (int rg = 0; rg < 4; ++rg) {
                    int r = mt * 16 + kg * 4 + rg;          // 0..79
                    int hi = (r >= 40);
                    int day = fi * 2 + hi;
                    int t = r - hi * 40;
                    gi2[((size_t)(s * 40 + t) * 10 + day) * 192 + col] = acc[mt][nc][rg] + bv;
                }
        }
    } else {
        // ================= bilinear quarter (unrolled x8) =================
        const int s = grp, kq = sub - 5;
        float* uT = (float*)sm;                       // [64][17] pad
        const int j4 = (l & 15) * 4;
        f4_t xq = *(const f4_t*)&xprice[s * Hn + j4];

        const float* Wbs = Wb + (size_t)s * Hn * Hn * Hn;
        for (int g = 0; g < 64; g += 8) {
            const int P0 = kq * 1024 + w * 256 + g * 4 + (l >> 4);
            f4_t wv0 = *(const f4_t*)&Wbs[(size_t)(P0)      * Hn + j4];
            f4_t wv1 = *(const f4_t*)&Wbs[(size_t)(P0 + 4)  * Hn + j4];
            f4_t wv2 = *(const f4_t*)&Wbs[(size_t)(P0 + 8)  * Hn + j4];
            f4_t wv3 = *(const f4_t*)&Wbs[(size_t)(P0 + 12) * Hn + j4];
            f4_t wv4 = *(const f4_t*)&Wbs[(size_t)(P0 + 16) * Hn + j4];
            f4_t wv5 = *(const f4_t*)&Wbs[(size_t)(P0 + 20) * Hn + j4];
            f4_t wv6 = *(const f4_t*)&Wbs[(size_t)(P0 + 24) * Hn + j4];
            f4_t wv7 = *(const f4_t*)&Wbs[(size_t)(P0 + 28) * Hn + j4];
            float d0 = wv0[0] * xq[0] + wv0[1] * xq[1] + wv0[2] * xq[2] + wv0[3] * xq[3];
            float d1 = wv1[0] * xq[0] + wv1[1] * xq[1] + wv1[2] * xq[2] + wv1[3] * xq[3];
            float d2 = wv2[0] * xq[0] + wv2[1] * xq[1] + wv2[2] * xq[2] + wv2[3] * xq[3];
            float d3 = wv3[0] * xq[0] + wv3[1] * xq[1] + wv3[2] * xq[2] + wv3[3] * xq[3];
            float d4 = wv4[0] * xq[0] + wv4[1] * xq[1] + wv4[2] * xq[2] + wv4[3] * xq[3];
            float d5 = wv5[0] * xq[0] + wv5[1] * xq[1] + wv5[2] * xq[2] + wv5[3] * xq[3];
            float d6 = wv6[0] * xq[0] + wv6[1] * xq[1] + wv6[2] * xq[2] + wv6[3] * xq[3];
            float d7 = wv7[0] * xq[0] + wv7[1] * xq[1] + wv7[2] * xq[2] + wv7[3] * xq[3];
            #pragma unroll
            for (int o = 8; o; o >>= 1) {
                d0 += __shfl_xor(d0, o);
                d1 += __shfl_xor(d1, o);
                d2 += __shfl_xor(d2, o);
                d3 += __shfl_xor(d3, o);
                d4 += __shfl_xor(d4, o);
                d5 += __shfl_xor(d5, o);
                d6 += __shfl_xor(d6, o);
                d7 += __shfl_xor(d7, o);
            }
            if ((l & 15) == 0) {
                float dv[8] = {d0, d1, d2, d3, d4, d5, d6, d7};
                #pragma unroll
                for (int q = 0; q < 8; ++q) {
                    int P = P0 + q * 4;
                    uT[(P & 63) * 17 + ((P >> 6) - kq * 16)] = dv[q];
                }
            }
        }
        __syncthreads();
        #pragma unroll
        for (int r = 0; r < 4; ++r) {
            int flat = tid + r * 256;
            int kr = flat >> 6, i = flat & 63;
            u[((size_t)s * 64 + kq * 16 + kr) * 64 + i] = uT[i * 17 + kr];
        }
    }
}

// ---------------------------------------------------------------------------
// gru_text_f: text GRU recurrence, 10 days batched in MFMA M-dim; Whh in
// VGPRs; fused online-softmax pooling -> news. Zero block barriers.
// ---------------------------------------------------------------------------
__global__ __launch_bounds__(64, 1) void gru_text_f(
    const float* __restrict__ gi2, const float* __restrict__ Whh,
    const float* __restrict__ bhh, const float* __restrict__ Wa,
    const float* __restrict__ va, float* __restrict__ news)
{
    __shared__ __align__(16) float hrow[16 * 68];
    __shared__ __align__(16) unsigned char waT[Hn * 128];

    const int s = blockIdx.x, l = threadIdx.x;
    const int lr = l & 15, lg = l >> 4;

    const float* Whhs = Whh + (size_t)s * Hn * G3;
    bfu bwhh[2][12];
    #pragma unroll
    for (int ks = 0; ks < 2; ++ks)
        #pragma unroll
        for (int nt = 0; nt < 12; ++nt) {
            const float* p = Whhs + (size_t)(ks * 32 + lg * 8) * G3 + nt * 16 + lr;
            float b0 = p[0], b1 = p[G3], b2 = p[2 * G3], b3 = p[3 * G3];
            float b4 = p[4 * G3], b5 = p[5 * G3], b6 = p[6 * G3], b7 = p[7 * G3];
            bwhh[ks][nt].u[0] = cvtpk(b0, b1); bwhh[ks][nt].u[1] = cvtpk(b2, b3);
            bwhh[ks][nt].u[2] = cvtpk(b4, b5); bwhh[ks][nt].u[3] = cvtpk(b6, b7);
        }
    float bhh_l[12];
    #pragma unroll
    for (int nt = 0; nt < 12; ++nt) bhh_l[nt] = bhh[(size_t)s * G3 + nt * 16 + lr];
    float va_l[4];
    #pragma unroll
    for (int nt = 0; nt < 4; ++nt) va_l[nt] = va[(size_t)s * Hn + nt * 16 + lr];

    {
        const float* Was = Wa + (size_t)s * Hn * Hn;
        for (int r = 0; r < 64; ++r) {
            int e = l + r * 64, i = e >> 6, k = e & 63;
            *(unsigned short*)(waT + k * 128 + ((2 * i) ^ ((k & 7) << 4))) = f2bf(Was[e]);
        }
        #pragma unroll
        for (int r = 0; r < 17; ++r) hrow[l + r * 64] = 0.f;
    }
    __builtin_amdgcn_wave_barrier();

    int dayoff[4];
    #pragma unroll
    for (int rr = 0; rr < 4; ++rr) {
        int d = lg * 4 + rr; if (d > 9) d = 9;
        dayoff[rr] = d * 192 + lr;
    }
    const float* gbase = gi2 + (size_t)s * 40 * 1920;

    float val[48], valn[48];
    #pragma unroll
    for (int j = 0; j < 48; ++j) val[j] = gbase[dayoff[j & 3] + (j >> 2) * 16];

    bf8_t a0f, a1f;
    {   bfu z0; z0.u[0] = 0; z0.u[1] = 0; z0.u[2] = 0; z0.u[3] = 0; a0f = z0.v; a1f = z0.v; }

    float h[4][4], accv[4][4], den[4], m[4];
    #pragma unroll
    for (int nt = 0; nt < 4; ++nt)
        #pragma unroll
        for (int rr = 0; rr < 4; ++rr) { h[nt][rr] = 0.f; accv[nt][rr] = 0.f; }
    #pragma unroll
    for (int rr = 0; rr < 4; ++rr) { den[rr] = 0.f; m[rr] = -1e30f; }

    for (int t = 0; t < Tn; ++t) {
        f4_t acc[12];
        #pragma unroll
        for (int nt = 0; nt < 12; ++nt)
            acc[nt] = (f4_t){bhh_l[nt], bhh_l[nt], bhh_l[nt], bhh_l[nt]};
        __builtin_amdgcn_s_setprio(1);
        #pragma unroll
        for (int nt = 0; nt < 12; ++nt) {
            acc[nt] = __builtin_amdgcn_mfma_f32_16x16x32_bf16(a0f, bwhh[0][nt].v, acc[nt], 0, 0, 0);
            acc[nt] = __builtin_amdgcn_mfma_f32_16x16x32_bf16(a1f, bwhh[1][nt].v, acc[nt], 0, 0, 0);
        }
        __builtin_amdgcn_s_setprio(0);
        {
            const int tn = (t < Tn - 1) ? t + 1 : t;
            const float* gb = gbase + (size_t)tn * 1920;
            #pragma unroll
            for (int j = 0; j < 48; ++j) valn[j] = gb[dayoff[j & 3] + (j >> 2) * 16];
        }
        #pragma unroll
        for (int nt = 0; nt < 4; ++nt)
            #pragma unroll
            for (int rr = 0; rr < 4; ++rr) {
                float r = sigmoidf_(val[nt * 4 + rr] + acc[nt][rr]);
                float z = sigmoidf_(val[(nt + 4) * 4 + rr] + acc[nt + 4][rr]);
                float n = tanhf_(val[(nt + 8) * 4 + rr] + r * acc[nt + 8][rr]);
                h[nt][rr] = (1.f - z) * n + z * h[nt][rr];
            }
        __builtin_amdgcn_wave_barrier();
        #pragma unroll
        for (int rr = 0; rr < 4; ++rr) {
            int day = lg * 4 + rr;
            if (day < Dn) {
                #pragma unroll
                for (int nt = 0; nt < 4; ++nt) hrow[day * 68 + nt * 16 + lr] = h[nt][rr];
            }
        }
        __builtin_amdgcn_wave_barrier();
        {
            const float* hp = hrow + lr * 68 + lg * 8;
            f4_t x0 = *(const f4_t*)hp,        x1 = *(const f4_t*)(hp + 4);
            f4_t y0 = *(const f4_t*)(hp + 32), y1 = *(const f4_t*)(hp + 36);
            bfu t0, t1;
            t0.u[0] = cvtpk(x0[0], x0[1]); t0.u[1] = cvtpk(x0[2], x0[3]);
            t0.u[2] = cvtpk(x1[0], x1[1]); t0.u[3] = cvtpk(x1[2], x1[3]);
            t1.u[0] = cvtpk(y0[0], y0[1]); t1.u[1] = cvtpk(y0[2], y0[3]);
            t1.u[2] = cvtpk(y1[0], y1[1]); t1.u[3] = cvtpk(y1[2], y1[3]);
            a0f = t0.v; a1f = t1.v;
        }
        f4_t sc[4];
        #pragma unroll
        for (int nt = 0; nt < 4; ++nt) sc[nt] = (f4_t){0.f, 0.f, 0.f, 0.f};
        __builtin_amdgcn_s_setprio(1);
        #pragma unroll
        for (int ks = 0; ks < 2; ++ks) {
            bf8_t av = ks ? a1f : a0f;
            #pragma unroll
            for (int nt = 0; nt < 4; ++nt) {
                bf8_t bwv = *(const bf8_t*)(waT + (nt * 16 + lr) * 128
                                            + ((ks * 64 + lg * 16) ^ ((lr & 7) << 4)));
                sc[nt] = __builtin_amdgcn_mfma_f32_16x16x32_bf16(av, bwv, sc[nt], 0, 0, 0);
            }
        }
        __builtin_amdgcn_s_setprio(0);
        float pr[4];
        #pragma unroll
        for (int rr = 0; rr < 4; ++rr) {
            pr[rr] = tanhf_(sc[0][rr]) * va_l[0] + tanhf_(sc[1][rr]) * va_l[1]
                   + tanhf_(sc[2][rr]) * va_l[2] + tanhf_(sc[3][rr]) * va_l[3];
            pr[rr] += __shfl_xor(pr[rr], 1);
            pr[rr] += __shfl_xor(pr[rr], 2);
            pr[rr] += __shfl_xor(pr[rr], 4);
            pr[rr] += __shfl_xor(pr[rr], 8);
        }
        #pragma unroll
        for (int rr = 0; rr < 4; ++rr) {
            float mn = fmaxf(m[rr], pr[rr]);
            float s0 = __expf(m[rr] - mn);
            float p = __expf(pr[rr] - mn);
            den[rr] = den[rr] * s0 + p;
            #pragma unroll
            for (int nt = 0; nt < 4; ++nt)
                accv[nt][rr] = accv[nt][rr] * s0 + p * h[nt][rr];
            m[rr] = mn;
        }
        #pragma unroll
        for (int j = 0; j < 48; ++j) val[j] = valn[j];
    }
    #pragma unroll
    for (int rr = 0; rr < 4; ++rr) {
        int day = lg * 4 + rr;
        if (day < Dn) {
            float inv = 1.f / den[rr];
            #pragma unroll
            for (int nt = 0; nt < 4; ++nt)
                news[((size_t)s * Dn + day) * Hn + nt * 16 + lr] = accv[nt][rr] * inv;
        }
    }
}

// ---------------------------------------------------------------------------
// day_finish: day-sequence GRU over news -> tvec (reg), then
// combined = tanh(tvec . u + bb), then q/k/out1. One 64-thr block per stock.
// ---------------------------------------------------------------------------
__global__ __launch_bounds__(64, 1) void day_finish(
    const float* __restrict__ news,
    const float* __restrict__ Wih_s, const float* __restrict__ Whh_s,
    const float* __restrict__ bih_s, const float* __restrict__ bhh_s,
    const float* __restrict__ Wa_s, const float* __restrict__ va_s,
    const float* __restrict__ u, const float* __restrict__ bb,
    const float* __restrict__ Wq, const float* __restrict__ bq,
    const float* __restrict__ Wk, const float* __restrict__ bk,
    const float* __restrict__ Wbl, const float* __restrict__ bbl,
    float* __restrict__ combined, float* __restrict__ qg,
    float* __restrict__ kg, float* __restrict__ out1)
{
    __shared__ __align__(16) unsigned char sm[60928];
    unsigned char* whh2 = sm;
    unsigned char* wih2 = sm + 24576;
    unsigned char* wa2 = sm + 49152;
    float* newsL = (float*)(sm + 57600);
    float* hbuf  = (float*)(sm + 60320);

    const int s = blockIdx.x, l = threadIdx.x;
    float tvv;

    {
        const float* W2 = Whh_s + (size_t)s * Hn * G3;
        const float* X2 = Wih_s + (size_t)s * Hn * G3;
        for (int r = 0; r < 192; ++r) {
            int e = l + r * 64, i = e / G3, j = e - i * G3;
            int off = j * 128 + ((2 * i) ^ ((j & 7) << 4));
            *(unsigned short*)(whh2 + off) = f2bf(W2[e]);
            *(unsigned short*)(wih2 + off) = f2bf(X2[e]);
        }
        const float* A2 = Wa_s + (size_t)s * Hn * Hn;
        for (int r = 0; r < 64; ++r) {
            int e = l + r * 64, i = e >> 6, k = e & 63;
            *(unsigned short*)(wa2 + k * 128 + ((2 * i) ^ ((k & 7) << 4))) = f2bf(A2[e]);
        }
        #pragma unroll
        for (int d = 0; d < Dn; ++d) newsL[d * 68 + l] = news[((size_t)s * Dn + d) * Hn + l];
        hbuf[l] = 0.f;
        if (l < 4) hbuf[64 + l] = 0.f;
    }
    __builtin_amdgcn_wave_barrier();
    {
        const float bi0 = bih_s[(size_t)s * G3 + l];
        const float bi1 = bih_s[(size_t)s * G3 + 64 + l];
        const float bi2 = bih_s[(size_t)s * G3 + 128 + l];
        const float bh0 = bhh_s[(size_t)s * G3 + l];
        const float bh1 = bhh_s[(size_t)s * G3 + 64 + l];
        const float bh2 = bhh_s[(size_t)s * G3 + 128 + l];
        const float vak = va_s[(size_t)s * Hn + l];
        const int swl = (l & 7) << 4;
        float h2 = 0.f, m2 = -1e30f, den2 = 0.f, av2 = 0.f;
        for (int t = 0; t < Dn; ++t) {
            float gh0 = bh0, gh1 = bh1, gh2 = bh2;
            float gg0 = bi0, gg1 = bi1, gg2 = bi2;
            #pragma unroll
            for (int ic = 0; ic < 8; ++ic) {
                const int off = (ic * 16) ^ swl;
                f4_t hA = *(const f4_t*)&hbuf[ic * 8];
                f4_t hB = *(const f4_t*)&hbuf[ic * 8 + 4];
                f4_t nA = *(const f4_t*)&newsL[t * 68 + ic * 8];
                f4_t nB = *(const f4_t*)&newsL[t * 68 + ic * 8 + 4];
                uint4 w0 = *(const uint4*)(whh2 + l * 128 + off);
                uint4 w1 = *(const uint4*)(whh2 + (l + 64) * 128 + off);
                uint4 w2 = *(const uint4*)(whh2 + (l + 128) * 128 + off);
                uint4 x0 = *(const uint4*)(wih2 + l * 128 + off);
                uint4 x1 = *(const uint4*)(wih2 + (l + 64) * 128 + off);
                uint4 x2 = *(const uint4*)(wih2 + (l + 128) * 128 + off);
                gh0 += dot8(w0, hA, hB); gh1 += dot8(w1, hA, hB); gh2 += dot8(w2, hA, hB);
                gg0 += dot8(x0, nA, nB); gg1 += dot8(x1, nA, nB); gg2 += dot8(x2, nA, nB);
            }
            float r = sigmoidf_(gg0 + gh0);
            float z = sigmoidf_(gg1 + gh1);
            float n = tanhf_(gg2 + r * gh2);
            h2 = (1.f - z) * n + z * h2;
            __builtin_amdgcn_wave_barrier();
            hbuf[l] = h2;
            __builtin_amdgcn_wave_barrier();
            float sk = 0.f;
            #pragma unroll
            for (int ic = 0; ic < 8; ++ic) {
                const int off = (ic * 16) ^ swl;
                uint4 wv = *(const uint4*)(wa2 + l * 128 + off);
                f4_t hA = *(const f4_t*)&hbuf[ic * 8];
                f4_t hB = *(const f4_t*)&hbuf[ic * 8 + 4];
                sk += dot8(wv, hA, hB);
            }
            float term = tanhf_(sk) * vak;
            #pragma unroll
            for (int off = 32; off; off >>= 1) term += __shfl_xor(term, off);
            float mn = fmaxf(m2, term);
            float s0 = __expf(m2 - mn);
            float p = __expf(term - mn);
            den2 = den2 * s0 + p;
            av2 = av2 * s0 + p * h2;
            m2 = mn;
        }
        tvv = av2 / den2;
    }
    __builtin_amdgcn_wave_barrier();

    float* uL = (float*)sm;              // [64][65]
    float* tvL = (float*)(sm + 16640);
    float* cl  = (float*)(sm + 16960);
    tvL[l] = tvv;
    const float* ub = u + (size_t)s * 4096;
    #pragma unroll 8
    for (int i = 0; i < 64; ++i) uL[i * 65 + l] = ub[i * 64 + l];
    __builtin_amdgcn_wave_barrier();
    {
        float a = bb[s * Hn + l];
        #pragma unroll 8
        for (int i = 0; i < 64; ++i) a += tvL[i] * uL[l * 65 + i];
        float c = tanhf_(a);
        cl[l] = c;
        combined[s * Hn + l] = c;
    }
    __builtin_amdgcn_wave_barrier();
    {
        float aq = bq[l], ak = bk[l];
        for (int i = 0; i < Hn; i++) {
            float ci = cl[i];
            aq += ci * Wq[i * Hn + l];
            ak += ci * Wk[i * Hn + l];
        }
        qg[s * Hn + l] = aq; kg[s * Hn + l] = ak;
        if (l < 2) {
            float a = bbl[s * 2 + l];
            for (int i = 0; i < Hn; i++) a += cl[i] * Wbl[(size_t)s * Hn * 2 + i * 2 + l];
            out1[s * 2 + l] = tanhf_(a);
        }
    }
}

// ---------------------------------------------------------------------------
// Cross-stock MHSA + elu head + blend + softmax.
// ---------------------------------------------------------------------------
__global__ __launch_bounds__(256) void mhsa(
    const float* __restrict__ qg, const float* __restrict__ kg,
    const float* __restrict__ combined, const float* __restrict__ Wf,
    const float* __restrict__ bfp, const float* __restrict__ out1,
    float* __restrict__ dout)
{
    __shared__ __align__(16) float ql[Hn];
    __shared__ float sl[NHn][Sn];
    __shared__ float hsum[NHn];
    __shared__ float ao[Hn];
    __shared__ float red2[8];
    __shared__ float red3[4][Hn];

    const int sq = blockIdx.x, tid = threadIdx.x;
    if (tid < Hn) ql[tid] = qg[sq * Hn + tid];
    __syncthreads();

    for (int id = tid; id < Sn * NHn; id += 256) {
        int t = id >> 2, h = id & 3;
        const float* kp = &kg[t * Hn + h * 16];
        float a = 0.f;
        #pragma unroll
        for (int x = 0; x < 16; x += 4) {
            f4_t kv = *(const f4_t*)&kp[x];
            f4_t qv = *(const f4_t*)&ql[h * 16 + x];
            a += kv[0] * qv[0] + kv[1] * qv[1] + kv[2] * qv[2] + kv[3] * qv[3];
        }
        sl[h][t] = a * 0.25f;
    }
    __syncthreads();
    for (int h = 0; h < NHn; ++h) {
        float m = -1e30f;
        for (int t = tid; t < Sn; t += 256) m = fmaxf(m, sl[h][t]);
        for (int o = 32; o; o >>= 1) m = fmaxf(m, __shfl_xor(m, o));
        if ((tid & 63) == 0) red2[tid >> 6] = m;
        __syncthreads();
        m = fmaxf(fmaxf(red2[0], red2[1]), fmaxf(red2[2], red2[3]));
        float ps = 0.f;
        for (int t = tid; t < Sn; t += 256) { float p = __expf(sl[h][t] - m); sl[h][t] = p; ps += p; }
        for (int o = 32; o; o >>= 1) ps += __shfl_xor(ps, o);
        if ((tid & 63) == 0) red2[4 + (tid >> 6)] = ps;
        __syncthreads();
        if (tid == 0) hsum[h] = red2[4] + red2[5] + red2[6] + red2[7];
        __syncthreads();
    }
    {
        const int q = tid >> 6, j = tid & 63, h = j >> 4;
        float a = 0.f;
        for (int t = q * 125; t < q * 125 + 125; ++t) a += sl[h][t] * combined[t * Hn + j];
        red3[q][j] = a;
    }
    __syncthreads();
    if (tid < Hn)
        ao[tid] = (red3[0][tid] + red3[1][tid] + red3[2][tid] + red3[3][tid]) / hsum[tid >> 4];
    __syncthreads();
    if (tid == 0) {
        float l0 = bfp[0], l1 = bfp[1];
        for (int j = 0; j < Hn; j++) { float v = ao[j]; l0 += v * Wf[j * 2]; l1 += v * Wf[j * 2 + 1]; }
        l0 = l0 > 0.f ? l0 : __expf(l0) - 1.f;
        l1 = l1 > 0.f ? l1 : __expf(l1) - 1.f;
        l0 += out1[sq * 2]; l1 += out1[sq * 2 + 1];
        float m = fmaxf(l0, l1);
        float e0 = __expf(l0 - m), e1 = __expf(l1 - m);
        float inv = 1.f / (e0 + e1);
        dout[1 + sq * 2] = e0 * inv;
        dout[2 + sq * 2] = e1 * inv;
    }
}

__global__ __launch_bounds__(512) void loss_k(float* __restrict__ dout,
                                              const int* __restrict__ label)
{
    __shared__ float red[512];
    const int tid = threadIdx.x;
    float a = 0.f;
    if (tid < Sn) {
        float p0 = dout[1 + 2 * tid], p1 = dout[2 + 2 * tid];
        float m = fmaxf(p0, p1);
        float lse = m + __logf(__expf(p0 - m) + __expf(p1 - m));
        float pl = label[tid] ? p1 : p0;
        a = -(pl - lse);
    }
    red[tid] = a;
    __syncthreads();
    for (int o = 256; o; o >>= 1) {
        if (tid < o) red[tid] += red[tid + o];
        __syncthreads();
    }
    if (tid == 0) dout[0] = red[0] / (float)Sn;
}

extern "C" void kernel_launch(void* const* d_in, const int* in_sizes, int n_in,
                              void* d_out, int out_size, void* d_ws, size_t ws_size,
                              hipStream_t stream)
{
    const float* text  = (const float*)d_in[0];
    const float* price = (const float*)d_in[1];
    const int*   label = (const int*)  d_in[2];
    const float* Wih_p = (const float*)d_in[5];
    const float* Whh_p = (const float*)d_in[6];
    const float* bih_p = (const float*)d_in[7];
    const float* bhh_p = (const float*)d_in[8];
    const float* Wa_p  = (const float*)d_in[9];
    const float* va_p  = (const float*)d_in[10];
    const float* Wih_t = (const float*)d_in[11];
    const float* Whh_t = (const float*)d_in[12];
    const float* bih_t = (const float*)d_in[13];
    const float* bhh_t = (const float*)d_in[14];
    const float* Wa_t  = (const float*)d_in[15];
    const float* va_t  = (const float*)d_in[16];
    const float* Wih_s = (const float*)d_in[17];
    const float* Whh_s = (const float*)d_in[18];
    const float* bih_s = (const float*)d_in[19];
    const float* bhh_s = (const float*)d_in[20];
    const float* Wa_s  = (const float*)d_in[21];
    const float* va_s  = (const float*)d_in[22];
    const float* Wb    = (const float*)d_in[23];
    const float* bb    = (const float*)d_in[24];
    const float* Wbl   = (const float*)d_in[25];
    const float* bbl   = (const float*)d_in[26];
    const float* Wq    = (const float*)d_in[27];
    const float* bq    = (const float*)d_in[28];
    const float* Wk    = (const float*)d_in[29];
    const float* bk    = (const float*)d_in[30];
    const float* Wf    = (const float*)d_in[31];
    const float* bf_   = (const float*)d_in[32];

    float* ws = (float*)d_ws;
    float* news     = ws;              // 320000
    float* xprice   = ws + 320000;     // 32000
    float* combined = ws + 384000;     // 32000
    float* qg       = ws + 416000;     // 32000
    float* kg       = ws + 448000;     // 32000
    float* out1     = ws + 480000;     // 1000
    float* u        = ws + 481000;     // 2,048,000 (8.2 MB)
    float* gi2      = ws + 2529000;    // 38,400,000 (153.6 MB)
    float* dout = (float*)d_out;

    price_gru<<<Sn, 64, 0, stream>>>(price, Wih_p, Whh_p, bih_p, bhh_p, Wa_p, va_p, xprice);
    k1_mega<<<4500, 256, 0, stream>>>(text, Wih_t, bih_t, gi2, Wb, xprice, u);
    gru_text_f<<<Sn, 64, 0, stream>>>(gi2, Whh_t, bhh_t, Wa_t, va_t, news);
    day_finish<<<Sn, 64, 0, stream>>>(news,
                                      Wih_s, Whh_s, bih_s, bhh_s, Wa_s, va_s,
                                      u, bb, Wq, bq, Wk, bk, Wbl, bbl,
                                      combined, qg, kg, out1);
    mhsa<<<Sn, 256, 0, stream>>>(qg, kg, combined, Wf, bf_, out1, dout);
    loss_k<<<1, 512, 0, stream>>>(dout, label);
}

// Round 19
// 552.109 us; speedup vs baseline: 1.0105x; 1.0105x over previous
//
#include <hip/hip_runtime.h>

#define Sn 500
#define Dn 10
#define Tn 40
#define FPn 3
#define FTn 512
#define Hn 64
#define G3 192
#define NHn 4

typedef __attribute__((ext_vector_type(8))) short bf8_t;   // 8 x bf16 bits
typedef __attribute__((ext_vector_type(4))) float f4_t;

__device__ __forceinline__ unsigned short f2bf(float f) {
    union { float f; unsigned int u; } v; v.f = f;
    unsigned int r = v.u + 0x7fffu + ((v.u >> 16) & 1u);
    return (unsigned short)(r >> 16);
}
__device__ __forceinline__ float bflo(unsigned int u) {
    union { unsigned int u; float f; } v; v.u = u << 16; return v.f;
}
__device__ __forceinline__ float bfhi(unsigned int u) {
    union { unsigned int u; float f; } v; v.u = u & 0xffff0000u; return v.f;
}
__device__ __forceinline__ unsigned int cvtpk(float lo, float hi) {
    unsigned int r;
    asm("v_cvt_pk_bf16_f32 %0, %1, %2" : "=v"(r) : "v"(lo), "v"(hi));
    return r;
}
__device__ __forceinline__ float sigmoidf_(float x) { return 1.f / (1.f + __expf(-x)); }
__device__ __forceinline__ float tanhf_(float x) {
    x = fminf(15.f, fmaxf(-15.f, x));
    float e = __expf(2.f * x);
    return (e - 1.f) / (e + 1.f);
}
__device__ __forceinline__ float dot8(uint4 wv, f4_t hA, f4_t hB) {
    return bflo(wv.x) * hA[0] + bfhi(wv.x) * hA[1]
         + bflo(wv.y) * hA[2] + bfhi(wv.y) * hA[3]
         + bflo(wv.z) * hB[0] + bfhi(wv.z) * hB[1]
         + bflo(wv.w) * hB[2] + bfhi(wv.w) * hB[3];
}
union bfu { bf8_t v; unsigned int u[4]; };

// ---------------------------------------------------------------------------
// price_gru: price GRU + attention pooling -> xprice. 500 blocks x 64 thr.
// Must complete before k1_mega (bilinear path reads xprice).
// ---------------------------------------------------------------------------
__global__ __launch_bounds__(64, 1) void price_gru(
    const float* __restrict__ price, const float* __restrict__ Wih_p,
    const float* __restrict__ Whh_p, const float* __restrict__ bih_p,
    const float* __restrict__ bhh_p, const float* __restrict__ Wa_p,
    const float* __restrict__ va_p, float* __restrict__ xprice)
{
    __shared__ __align__(16) unsigned char smp[33160];
    unsigned char* whh2 = smp;                    // [192][128B]
    unsigned char* wa2 = smp + 24576;             // [64][128B]
    float* hbuf = (float*)(smp + 32768);          // [68]
    float* priceL = (float*)(smp + 33040);        // [30]

    const int s = blockIdx.x, l = threadIdx.x;
    {
        const float* W3 = Whh_p + (size_t)s * Hn * G3;
        for (int r = 0; r < 192; ++r) {
            int e = l + r * 64, i = e / G3, j = e - i * G3;
            *(unsigned short*)(whh2 + j * 128 + ((2 * i) ^ ((j & 7) << 4))) = f2bf(W3[e]);
        }
        const float* A3 = Wa_p + (size_t)s * Hn * Hn;
        for (int r = 0; r < 64; ++r) {
            int e = l + r * 64, i = e >> 6, k = e & 63;
            *(unsigned short*)(wa2 + k * 128 + ((2 * i) ^ ((k & 7) << 4))) = f2bf(A3[e]);
        }
        if (l < 30) priceL[l] = price[(size_t)s * 30 + l];
        hbuf[l] = 0.f;
        if (l < 4) hbuf[64 + l] = 0.f;
    }
    __builtin_amdgcn_wave_barrier();
    {
        float wp[3][3];
        #pragma unroll
        for (int i = 0; i < 3; ++i)
            #pragma unroll
            for (int g = 0; g < 3; ++g)
                wp[i][g] = Wih_p[(size_t)s * 3 * G3 + i * G3 + g * 64 + l];
        const float bi0 = bih_p[(size_t)s * G3 + l];
        const float bi1 = bih_p[(size_t)s * G3 + 64 + l];
        const float bi2 = bih_p[(size_t)s * G3 + 128 + l];
        const float bh0 = bhh_p[(size_t)s * G3 + l];
        const float bh1 = bhh_p[(size_t)s * G3 + 64 + l];
        const float bh2 = bhh_p[(size_t)s * G3 + 128 + l];
        const float vak = va_p[(size_t)s * Hn + l];
        const int swl = (l & 7) << 4;
        float h3 = 0.f, m3 = -1e30f, den3 = 0.f, av3 = 0.f;
        for (int t = 0; t < Dn; ++t) {
            float x0 = priceL[t * 3], x1 = priceL[t * 3 + 1], x2 = priceL[t * 3 + 2];
            float gg0 = bi0 + x0 * wp[0][0] + x1 * wp[1][0] + x2 * wp[2][0];
            float gg1 = bi1 + x0 * wp[0][1] + x1 * wp[1][1] + x2 * wp[2][1];
            float gg2 = bi2 + x0 * wp[0][2] + x1 * wp[1][2] + x2 * wp[2][2];
            float gh0 = bh0, gh1 = bh1, gh2 = bh2;
            #pragma unroll
            for (int ic = 0; ic < 8; ++ic) {
                const int off = (ic * 16) ^ swl;
                f4_t hA = *(const f4_t*)&hbuf[ic * 8];
                f4_t hB = *(const f4_t*)&hbuf[ic * 8 + 4];
                uint4 w0 = *(const uint4*)(whh2 + l * 128 + off);
                uint4 w1 = *(const uint4*)(whh2 + (l + 64) * 128 + off);
                uint4 w2 = *(const uint4*)(whh2 + (l + 128) * 128 + off);
                gh0 += dot8(w0, hA, hB); gh1 += dot8(w1, hA, hB); gh2 += dot8(w2, hA, hB);
            }
            float r = sigmoidf_(gg0 + gh0);
            float z = sigmoidf_(gg1 + gh1);
            float n = tanhf_(gg2 + r * gh2);
            h3 = (1.f - z) * n + z * h3;
            __builtin_amdgcn_wave_barrier();
            hbuf[l] = h3;
            __builtin_amdgcn_wave_barrier();
            float sk = 0.f;
            #pragma unroll
            for (int ic = 0; ic < 8; ++ic) {
                const int off = (ic * 16) ^ swl;
                uint4 wv = *(const uint4*)(wa2 + l * 128 + off);
                f4_t hA = *(const f4_t*)&hbuf[ic * 8];
                f4_t hB = *(const f4_t*)&hbuf[ic * 8 + 4];
                sk += dot8(wv, hA, hB);
            }
            float term = tanhf_(sk) * vak;
            #pragma unroll
            for (int off = 32; off; off >>= 1) term += __shfl_xor(term, off);
            float mn = fmaxf(m3, term);
            float s0 = __expf(m3 - mn);
            float p = __expf(term - mn);
            den3 = den3 * s0 + p;
            av3 = av3 * s0 + p * h3;
            m3 = mn;
        }
        xprice[(size_t)s * Hn + l] = av3 / den3;
    }
}

// ---------------------------------------------------------------------------
// k1_mega: 4500 blocks, 9 per stock (XCD-bijective swizzle groups a stock's
// blocks on one XCD so Wih stays L2-hot):
//   sub 0..4 -> gi GEMM fifth (80 rows), BK=32, ALL-coalesced A+B LDS staging,
//               issue-early/write-late.
//   sub 5..8 -> bilinear quarter: u[s][k][i] = sum_j Wb[s,k,i,j]*xprice[j].
//               g-loop UNROLLED x4 with batched loads (r17-proven: -26us;
//               x8 measured neutral, so x4 is final).
// ---------------------------------------------------------------------------
__global__ __launch_bounds__(256) void k1_mega(
    const float* __restrict__ text, const float* __restrict__ Wih,
    const float* __restrict__ bih, float* __restrict__ gi2,
    const float* __restrict__ Wb, const float* __restrict__ xprice,
    float* __restrict__ u)
{
    __shared__ __align__(16) unsigned char sm[18688];

    const int bid = blockIdx.x, tid = threadIdx.x;
    const int xcd = bid & 7, ix = bid >> 3;
    // bijective XCD swizzle, nwg=4500: q=562, r=4
    const int swz = (xcd < 4 ? xcd * 563 : 2252 + (xcd - 4) * 562) + ix;
    const int grp = swz / 9, sub = swz - grp * 9;
    const int w = tid >> 6, l = tid & 63;

    if (sub < 5) {
        // ================= gi GEMM =================
        const int s = grp, fi = sub;
        const int lr = l & 15, kg = l >> 4;
        unsigned short* Asb = (unsigned short*)sm;            // [80][40] bf16
        unsigned char*  Bsb = sm + 6400;                      // 4 x [192][16B]

        const float* xbase = text + ((size_t)s * 400 + fi * 80) * FTn;
        const float* Wihs  = Wih + (size_t)s * FTn * G3;

        f4_t acc[5][3];
        #pragma unroll
        for (int a = 0; a < 5; a++)
            #pragma unroll
            for (int b = 0; b < 3; b++) acc[a][b] = (f4_t){0.f, 0.f, 0.f, 0.f};

        f4_t pa[3];            // A staging: 640 tasks (row,chunk)
        f4_t pb0[3], pb1[3];   // B staging: 768 tasks (kpair, colquad)

        auto aload = [&](int kk) {
            #pragma unroll
            for (int q = 0; q < 3; ++q) {
                int t = tid + q * 256;
                if (q < 2 || tid < 128) {
                    int row = t >> 3, ch = t & 7;
                    pa[q] = *(const f4_t*)(xbase + (size_t)row * FTn + kk * 32 + ch * 4);
                }
            }
        };
        auto bload = [&](int kk) {
            #pragma unroll
            for (int q = 0; q < 3; ++q) {
                int t = tid + q * 256;
                int kp = t / 48, cq = t % 48;
                const float* p = Wihs + (size_t)(kk * 32 + 2 * kp) * G3 + cq * 4;
                pb0[q] = *(const f4_t*)p;
                pb1[q] = *(const f4_t*)(p + G3);
            }
        };
        auto awrite = [&]() {
            #pragma unroll
            for (int q = 0; q < 3; ++q) {
                int t = tid + q * 256;
                if (q < 2 || tid < 128) {
                    int row = t >> 3, ch = t & 7;
                    uint2 uu = { cvtpk(pa[q][0], pa[q][1]), cvtpk(pa[q][2], pa[q][3]) };
                    *(uint2*)((unsigned char*)Asb + row * 80 + ch * 8) = uu;
                }
            }
        };
        auto bwrite = [&]() {
            #pragma unroll
            for (int q = 0; q < 3; ++q) {
                int t = tid + q * 256;
                int kp = t / 48, cq = t % 48;
                int base = (kp >> 2) * 3072 + (kp & 3) * 4;
                #pragma unroll
                for (int i = 0; i < 4; ++i) {
                    int col = cq * 4 + i;
                    int colp = col ^ ((col >> 2) & 7);     // bijective bank swizzle
                    *(unsigned int*)(Bsb + base + colp * 16) = cvtpk(pb0[q][i], pb1[q][i]);
                }
            }
        };

        aload(0); bload(0);
        for (int kk = 0; kk < 16; ++kk) {
            awrite(); bwrite();
            __syncthreads();
            if (kk < 15) { aload(kk + 1); bload(kk + 1); }   // issue-early (T14)
            bf8_t bfr[3];
            #pragma unroll
            for (int nc = 0; nc < 3; ++nc) {
                int col = w * 48 + nc * 16 + lr;
                int colp = col ^ ((col >> 2) & 7);
                bfr[nc] = *(const bf8_t*)(Bsb + kg * 3072 + colp * 16);
            }
            #pragma unroll
            for (int mt = 0; mt < 5; ++mt) {
                bf8_t af = *(const bf8_t*)((unsigned char*)Asb + (mt * 16 + lr) * 80 + kg * 16);
                acc[mt][0] = __builtin_amdgcn_mfma_f32_16x16x32_bf16(af, bfr[0], acc[mt][0], 0, 0, 0);
                acc[mt][1] = __builtin_amdgcn_mfma_f32_16x16x32_bf16(af, bfr[1], acc[mt][1], 0, 0, 0);
                acc[mt][2] = __builtin_amdgcn_mfma_f32_16x16x32_bf16(af, bfr[2], acc[mt][2], 0, 0, 0);
            }
            __syncthreads();
        }

        const float* bihs = bih + (size_t)s * G3 + w * 48 + lr;
        #pragma unroll
        for (int nc = 0; nc < 3; ++nc) {
            const int col = w * 48 + nc * 16 + lr;
            const float bv = bihs[nc * 16];
            #pragma unroll
            for (int mt = 0; mt < 5; ++mt)
                #pragma unroll
                for (int rg = 0; rg < 4; ++rg) {
                    int r = mt * 16 + kg * 4 + rg;          // 0..79
                    int hi = (r >= 40);
                    int day = fi * 2 + hi;
                    int t = r - hi * 40;
                    gi2[((size_t)(s * 40 + t) * 10 + day) * 192 + col] = acc[mt][nc][rg] + bv;
                }
        }
    } else {
        // ================= bilinear quarter (unrolled x4) =================
        const int s = grp, kq = sub - 5;
        float* uT = (float*)sm;                       // [64][17] pad
        const int j4 = (l & 15) * 4;
        f4_t xq = *(const f4_t*)&xprice[s * Hn + j4];

        const float* Wbs = Wb + (size_t)s * Hn * Hn * Hn;
        for (int g = 0; g < 64; g += 4) {
            const int P0 = kq * 1024 + w * 256 + g * 4 + (l >> 4);
            f4_t wv0 = *(const f4_t*)&Wbs[(size_t)(P0)      * Hn + j4];
            f4_t wv1 = *(const f4_t*)&Wbs[(size_t)(P0 + 4)  * Hn + j4];
            f4_t wv2 = *(const f4_t*)&Wbs[(size_t)(P0 + 8)  * Hn + j4];
            f4_t wv3 = *(const f4_t*)&Wbs[(size_t)(P0 + 12) * Hn + j4];
            float d0 = wv0[0] * xq[0] + wv0[1] * xq[1] + wv0[2] * xq[2] + wv0[3] * xq[3];
            float d1 = wv1[0] * xq[0] + wv1[1] * xq[1] + wv1[2] * xq[2] + wv1[3] * xq[3];
            float d2 = wv2[0] * xq[0] + wv2[1] * xq[1] + wv2[2] * xq[2] + wv2[3] * xq[3];
            float d3 = wv3[0] * xq[0] + wv3[1] * xq[1] + wv3[2] * xq[2] + wv3[3] * xq[3];
            #pragma unroll
            for (int o = 8; o; o >>= 1) {
                d0 += __shfl_xor(d0, o);
                d1 += __shfl_xor(d1, o);
                d2 += __shfl_xor(d2, o);
                d3 += __shfl_xor(d3, o);
            }
            if ((l & 15) == 0) {
                int k0 = P0 >> 6, i0 = P0 & 63;
                uT[i0 * 17 + (k0 - kq * 16)] = d0;
                int P1 = P0 + 4, P2 = P0 + 8, P3 = P0 + 12;
                uT[(P1 & 63) * 17 + ((P1 >> 6) - kq * 16)] = d1;
                uT[(P2 & 63) * 17 + ((P2 >> 6) - kq * 16)] = d2;
                uT[(P3 & 63) * 17 + ((P3 >> 6) - kq * 16)] = d3;
            }
        }
        __syncthreads();
        #pragma unroll
        for (int r = 0; r < 4; ++r) {
            int flat = tid + r * 256;
            int kr = flat >> 6, i = flat & 63;
            u[((size_t)s * 64 + kq * 16 + kr) * 64 + i] = uT[i * 17 + kr];
        }
    }
}

// ---------------------------------------------------------------------------
// gru_text_f: text GRU recurrence, 10 days batched in MFMA M-dim; Whh in
// VGPRs; fused online-softmax pooling -> news. Zero block barriers.
// ---------------------------------------------------------------------------
__global__ __launch_bounds__(64, 1) void gru_text_f(
    const float* __restrict__ gi2, const float* __restrict__ Whh,
    const float* __restrict__ bhh, const float* __restrict__ Wa,
    const float* __restrict__ va, float* __restrict__ news)
{
    __shared__ __align__(16) float hrow[16 * 68];
    __shared__ __align__(16) unsigned char waT[Hn * 128];

    const int s = blockIdx.x, l = threadIdx.x;
    const int lr = l & 15, lg = l >> 4;

    const float* Whhs = Whh + (size_t)s * Hn * G3;
    bfu bwhh[2][12];
    #pragma unroll
    for (int ks = 0; ks < 2; ++ks)
        #pragma unroll
        for (int nt = 0; nt < 12; ++nt) {
            const float* p = Whhs + (size_t)(ks * 32 + lg * 8) * G3 + nt * 16 + lr;
            float b0 = p[0], b1 = p[G3], b2 = p[2 * G3], b3 = p[3 * G3];
            float b4 = p[4 * G3], b5 = p[5 * G3], b6 = p[6 * G3], b7 = p[7 * G3];
            bwhh[ks][nt].u[0] = cvtpk(b0, b1); bwhh[ks][nt].u[1] = cvtpk(b2, b3);
            bwhh[ks][nt].u[2] = cvtpk(b4, b5); bwhh[ks][nt].u[3] = cvtpk(b6, b7);
        }
    float bhh_l[12];
    #pragma unroll
    for (int nt = 0; nt < 12; ++nt) bhh_l[nt] = bhh[(size_t)s * G3 + nt * 16 + lr];
    float va_l[4];
    #pragma unroll
    for (int nt = 0; nt < 4; ++nt) va_l[nt] = va[(size_t)s * Hn + nt * 16 + lr];

    {
        const float* Was = Wa + (size_t)s * Hn * Hn;
        for (int r = 0; r < 64; ++r) {
            int e = l + r * 64, i = e >> 6, k = e & 63;
            *(unsigned short*)(waT + k * 128 + ((2 * i) ^ ((k & 7) << 4))) = f2bf(Was[e]);
        }
        #pragma unroll
        for (int r = 0; r < 17; ++r) hrow[l + r * 64] = 0.f;
    }
    __builtin_amdgcn_wave_barrier();

    int dayoff[4];
    #pragma unroll
    for (int rr = 0; rr < 4; ++rr) {
        int d = lg * 4 + rr; if (d > 9) d = 9;
        dayoff[rr] = d * 192 + lr;
    }
    const float* gbase = gi2 + (size_t)s * 40 * 1920;

    float val[48], valn[48];
    #pragma unroll
    for (int j = 0; j < 48; ++j) val[j] = gbase[dayoff[j & 3] + (j >> 2) * 16];

    bf8_t a0f, a1f;
    {   bfu z0; z0.u[0] = 0; z0.u[1] = 0; z0.u[2] = 0; z0.u[3] = 0; a0f = z0.v; a1f = z0.v; }

    float h[4][4], accv[4][4], den[4], m[4];
    #pragma unroll
    for (int nt = 0; nt < 4; ++nt)
        #pragma unroll
        for (int rr = 0; rr < 4; ++rr) { h[nt][rr] = 0.f; accv[nt][rr] = 0.f; }
    #pragma unroll
    for (int rr = 0; rr < 4; ++rr) { den[rr] = 0.f; m[rr] = -1e30f; }

    for (int t = 0; t < Tn; ++t) {
        f4_t acc[12];
        #pragma unroll
        for (int nt = 0; nt < 12; ++nt)
            acc[nt] = (f4_t){bhh_l[nt], bhh_l[nt], bhh_l[nt], bhh_l[nt]};
        __builtin_amdgcn_s_setprio(1);
        #pragma unroll
        for (int nt = 0; nt < 12; ++nt) {
            acc[nt] = __builtin_amdgcn_mfma_f32_16x16x32_bf16(a0f, bwhh[0][nt].v, acc[nt], 0, 0, 0);
            acc[nt] = __builtin_amdgcn_mfma_f32_16x16x32_bf16(a1f, bwhh[1][nt].v, acc[nt], 0, 0, 0);
        }
        __builtin_amdgcn_s_setprio(0);
        {
            const int tn = (t < Tn - 1) ? t + 1 : t;
            const float* gb = gbase + (size_t)tn * 1920;
            #pragma unroll
            for (int j = 0; j < 48; ++j) valn[j] = gb[dayoff[j & 3] + (j >> 2) * 16];
        }
        #pragma unroll
        for (int nt = 0; nt < 4; ++nt)
            #pragma unroll
            for (int rr = 0; rr < 4; ++rr) {
                float r = sigmoidf_(val[nt * 4 + rr] + acc[nt][rr]);
                float z = sigmoidf_(val[(nt + 4) * 4 + rr] + acc[nt + 4][rr]);
                float n = tanhf_(val[(nt + 8) * 4 + rr] + r * acc[nt + 8][rr]);
                h[nt][rr] = (1.f - z) * n + z * h[nt][rr];
            }
        __builtin_amdgcn_wave_barrier();
        #pragma unroll
        for (int rr = 0; rr < 4; ++rr) {
            int day = lg * 4 + rr;
            if (day < Dn) {
                #pragma unroll
                for (int nt = 0; nt < 4; ++nt) hrow[day * 68 + nt * 16 + lr] = h[nt][rr];
            }
        }
        __builtin_amdgcn_wave_barrier();
        {
            const float* hp = hrow + lr * 68 + lg * 8;
            f4_t x0 = *(const f4_t*)hp,        x1 = *(const f4_t*)(hp + 4);
            f4_t y0 = *(const f4_t*)(hp + 32), y1 = *(const f4_t*)(hp + 36);
            bfu t0, t1;
            t0.u[0] = cvtpk(x0[0], x0[1]); t0.u[1] = cvtpk(x0[2], x0[3]);
            t0.u[2] = cvtpk(x1[0], x1[1]); t0.u[3] = cvtpk(x1[2], x1[3]);
            t1.u[0] = cvtpk(y0[0], y0[1]); t1.u[1] = cvtpk(y0[2], y0[3]);
            t1.u[2] = cvtpk(y1[0], y1[1]); t1.u[3] = cvtpk(y1[2], y1[3]);
            a0f = t0.v; a1f = t1.v;
        }
        f4_t sc[4];
        #pragma unroll
        for (int nt = 0; nt < 4; ++nt) sc[nt] = (f4_t){0.f, 0.f, 0.f, 0.f};
        __builtin_amdgcn_s_setprio(1);
        #pragma unroll
        for (int ks = 0; ks < 2; ++ks) {
            bf8_t av = ks ? a1f : a0f;
            #pragma unroll
            for (int nt = 0; nt < 4; ++nt) {
                bf8_t bwv = *(const bf8_t*)(waT + (nt * 16 + lr) * 128
                                            + ((ks * 64 + lg * 16) ^ ((lr & 7) << 4)));
                sc[nt] = __builtin_amdgcn_mfma_f32_16x16x32_bf16(av, bwv, sc[nt], 0, 0, 0);
            }
        }
        __builtin_amdgcn_s_setprio(0);
        float pr[4];
        #pragma unroll
        for (int rr = 0; rr < 4; ++rr) {
            pr[rr] = tanhf_(sc[0][rr]) * va_l[0] + tanhf_(sc[1][rr]) * va_l[1]
                   + tanhf_(sc[2][rr]) * va_l[2] + tanhf_(sc[3][rr]) * va_l[3];
            pr[rr] += __shfl_xor(pr[rr], 1);
            pr[rr] += __shfl_xor(pr[rr], 2);
            pr[rr] += __shfl_xor(pr[rr], 4);
            pr[rr] += __shfl_xor(pr[rr], 8);
        }
        #pragma unroll
        for (int rr = 0; rr < 4; ++rr) {
            float mn = fmaxf(m[rr], pr[rr]);
            float s0 = __expf(m[rr] - mn);
            float p = __expf(pr[rr] - mn);
            den[rr] = den[rr] * s0 + p;
            #pragma unroll
            for (int nt = 0; nt < 4; ++nt)
                accv[nt][rr] = accv[nt][rr] * s0 + p * h[nt][rr];
            m[rr] = mn;
        }
        #pragma unroll
        for (int j = 0; j < 48; ++j) val[j] = valn[j];
    }
    #pragma unroll
    for (int rr = 0; rr < 4; ++rr) {
        int day = lg * 4 + rr;
        if (day < Dn) {
            float inv = 1.f / den[rr];
            #pragma unroll
            for (int nt = 0; nt < 4; ++nt)
                news[((size_t)s * Dn + day) * Hn + nt * 16 + lr] = accv[nt][rr] * inv;
        }
    }
}

// ---------------------------------------------------------------------------
// day_finish: day-sequence GRU over news -> tvec (reg), then
// combined = tanh(tvec . u + bb), then q/k/out1. One 64-thr block per stock.
// ---------------------------------------------------------------------------
__global__ __launch_bounds__(64, 1) void day_finish(
    const float* __restrict__ news,
    const float* __restrict__ Wih_s, const float* __restrict__ Whh_s,
    const float* __restrict__ bih_s, const float* __restrict__ bhh_s,
    const float* __restrict__ Wa_s, const float* __restrict__ va_s,
    const float* __restrict__ u, const float* __restrict__ bb,
    const float* __restrict__ Wq, const float* __restrict__ bq,
    const float* __restrict__ Wk, const float* __restrict__ bk,
    const float* __restrict__ Wbl, const float* __restrict__ bbl,
    float* __restrict__ combined, float* __restrict__ qg,
    float* __restrict__ kg, float* __restrict__ out1)
{
    __shared__ __align__(16) unsigned char sm[60928];
    unsigned char* whh2 = sm;
    unsigned char* wih2 = sm + 24576;
    unsigned char* wa2 = sm + 49152;
    float* newsL = (float*)(sm + 57600);
    float* hbuf  = (float*)(sm + 60320);

    const int s = blockIdx.x, l = threadIdx.x;
    float tvv;

    {
        const float* W2 = Whh_s + (size_t)s * Hn * G3;
        const float* X2 = Wih_s + (size_t)s * Hn * G3;
        for (int r = 0; r < 192; ++r) {
            int e = l + r * 64, i = e / G3, j = e - i * G3;
            int off = j * 128 + ((2 * i) ^ ((j & 7) << 4));
            *(unsigned short*)(whh2 + off) = f2bf(W2[e]);
            *(unsigned short*)(wih2 + off) = f2bf(X2[e]);
        }
        const float* A2 = Wa_s + (size_t)s * Hn * Hn;
        for (int r = 0; r < 64; ++r) {
            int e = l + r * 64, i = e >> 6, k = e & 63;
            *(unsigned short*)(wa2 + k * 128 + ((2 * i) ^ ((k & 7) << 4))) = f2bf(A2[e]);
        }
        #pragma unroll
        for (int d = 0; d < Dn; ++d) newsL[d * 68 + l] = news[((size_t)s * Dn + d) * Hn + l];
        hbuf[l] = 0.f;
        if (l < 4) hbuf[64 + l] = 0.f;
    }
    __builtin_amdgcn_wave_barrier();
    {
        const float bi0 = bih_s[(size_t)s * G3 + l];
        const float bi1 = bih_s[(size_t)s * G3 + 64 + l];
        const float bi2 = bih_s[(size_t)s * G3 + 128 + l];
        const float bh0 = bhh_s[(size_t)s * G3 + l];
        const float bh1 = bhh_s[(size_t)s * G3 + 64 + l];
        const float bh2 = bhh_s[(size_t)s * G3 + 128 + l];
        const float vak = va_s[(size_t)s * Hn + l];
        const int swl = (l & 7) << 4;
        float h2 = 0.f, m2 = -1e30f, den2 = 0.f, av2 = 0.f;
        for (int t = 0; t < Dn; ++t) {
            float gh0 = bh0, gh1 = bh1, gh2 = bh2;
            float gg0 = bi0, gg1 = bi1, gg2 = bi2;
            #pragma unroll
            for (int ic = 0; ic < 8; ++ic) {
                const int off = (ic * 16) ^ swl;
                f4_t hA = *(const f4_t*)&hbuf[ic * 8];
                f4_t hB = *(const f4_t*)&hbuf[ic * 8 + 4];
                f4_t nA = *(const f4_t*)&newsL[t * 68 + ic * 8];
                f4_t nB = *(const f4_t*)&newsL[t * 68 + ic * 8 + 4];
                uint4 w0 = *(const uint4*)(whh2 + l * 128 + off);
                uint4 w1 = *(const uint4*)(whh2 + (l + 64) * 128 + off);
                uint4 w2 = *(const uint4*)(whh2 + (l + 128) * 128 + off);
                uint4 x0 = *(const uint4*)(wih2 + l * 128 + off);
                uint4 x1 = *(const uint4*)(wih2 + (l + 64) * 128 + off);
                uint4 x2 = *(const uint4*)(wih2 + (l + 128) * 128 + off);
                gh0 += dot8(w0, hA, hB); gh1 += dot8(w1, hA, hB); gh2 += dot8(w2, hA, hB);
                gg0 += dot8(x0, nA, nB); gg1 += dot8(x1, nA, nB); gg2 += dot8(x2, nA, nB);
            }
            float r = sigmoidf_(gg0 + gh0);
            float z = sigmoidf_(gg1 + gh1);
            float n = tanhf_(gg2 + r * gh2);
            h2 = (1.f - z) * n + z * h2;
            __builtin_amdgcn_wave_barrier();
            hbuf[l] = h2;
            __builtin_amdgcn_wave_barrier();
            float sk = 0.f;
            #pragma unroll
            for (int ic = 0; ic < 8; ++ic) {
                const int off = (ic * 16) ^ swl;
                uint4 wv = *(const uint4*)(wa2 + l * 128 + off);
                f4_t hA = *(const f4_t*)&hbuf[ic * 8];
                f4_t hB = *(const f4_t*)&hbuf[ic * 8 + 4];
                sk += dot8(wv, hA, hB);
            }
            float term = tanhf_(sk) * vak;
            #pragma unroll
            for (int off = 32; off; off >>= 1) term += __shfl_xor(term, off);
            float mn = fmaxf(m2, term);
            float s0 = __expf(m2 - mn);
            float p = __expf(term - mn);
            den2 = den2 * s0 + p;
            av2 = av2 * s0 + p * h2;
            m2 = mn;
        }
        tvv = av2 / den2;
    }
    __builtin_amdgcn_wave_barrier();

    float* uL = (float*)sm;              // [64][65]
    float* tvL = (float*)(sm + 16640);
    float* cl  = (float*)(sm + 16960);
    tvL[l] = tvv;
    const float* ub = u + (size_t)s * 4096;
    #pragma unroll 8
    for (int i = 0; i < 64; ++i) uL[i * 65 + l] = ub[i * 64 + l];
    __builtin_amdgcn_wave_barrier();
    {
        float a = bb[s * Hn + l];
        #pragma unroll 8
        for (int i = 0; i < 64; ++i) a += tvL[i] * uL[l * 65 + i];
        float c = tanhf_(a);
        cl[l] = c;
        combined[s * Hn + l] = c;
    }
    __builtin_amdgcn_wave_barrier();
    {
        float aq = bq[l], ak = bk[l];
        for (int i = 0; i < Hn; i++) {
            float ci = cl[i];
            aq += ci * Wq[i * Hn + l];
            ak += ci * Wk[i * Hn + l];
        }
        qg[s * Hn + l] = aq; kg[s * Hn + l] = ak;
        if (l < 2) {
            float a = bbl[s * 2 + l];
            for (int i = 0; i < Hn; i++) a += cl[i] * Wbl[(size_t)s * Hn * 2 + i * 2 + l];
            out1[s * 2 + l] = tanhf_(a);
        }
    }
}

// ---------------------------------------------------------------------------
// Cross-stock MHSA + elu head + blend + softmax.
// ---------------------------------------------------------------------------
__global__ __launch_bounds__(256) void mhsa(
    const float* __restrict__ qg, const float* __restrict__ kg,
    const float* __restrict__ combined, const float* __restrict__ Wf,
    const float* __restrict__ bfp, const float* __restrict__ out1,
    float* __restrict__ dout)
{
    __shared__ __align__(16) float ql[Hn];
    __shared__ float sl[NHn][Sn];
    __shared__ float hsum[NHn];
    __shared__ float ao[Hn];
    __shared__ float red2[8];
    __shared__ float red3[4][Hn];

    const int sq = blockIdx.x, tid = threadIdx.x;
    if (tid < Hn) ql[tid] = qg[sq * Hn + tid];
    __syncthreads();

    for (int id = tid; id < Sn * NHn; id += 256) {
        int t = id >> 2, h = id & 3;
        const float* kp = &kg[t * Hn + h * 16];
        float a = 0.f;
        #pragma unroll
        for (int x = 0; x < 16; x += 4) {
            f4_t kv = *(const f4_t*)&kp[x];
            f4_t qv = *(const f4_t*)&ql[h * 16 + x];
            a += kv[0] * qv[0] + kv[1] * qv[1] + kv[2] * qv[2] + kv[3] * qv[3];
        }
        sl[h][t] = a * 0.25f;
    }
    __syncthreads();
    for (int h = 0; h < NHn; ++h) {
        float m = -1e30f;
        for (int t = tid; t < Sn; t += 256) m = fmaxf(m, sl[h][t]);
        for (int o = 32; o; o >>= 1) m = fmaxf(m, __shfl_xor(m, o));
        if ((tid & 63) == 0) red2[tid >> 6] = m;
        __syncthreads();
        m = fmaxf(fmaxf(red2[0], red2[1]), fmaxf(red2[2], red2[3]));
        float ps = 0.f;
        for (int t = tid; t < Sn; t += 256) { float p = __expf(sl[h][t] - m); sl[h][t] = p; ps += p; }
        for (int o = 32; o; o >>= 1) ps += __shfl_xor(ps, o);
        if ((tid & 63) == 0) red2[4 + (tid >> 6)] = ps;
        __syncthreads();
        if (tid == 0) hsum[h] = red2[4] + red2[5] + red2[6] + red2[7];
        __syncthreads();
    }
    {
        const int q = tid >> 6, j = tid & 63, h = j >> 4;
        float a = 0.f;
        for (int t = q * 125; t < q * 125 + 125; ++t) a += sl[h][t] * combined[t * Hn + j];
        red3[q][j] = a;
    }
    __syncthreads();
    if (tid < Hn)
        ao[tid] = (red3[0][tid] + red3[1][tid] + red3[2][tid] + red3[3][tid]) / hsum[tid >> 4];
    __syncthreads();
    if (tid == 0) {
        float l0 = bfp[0], l1 = bfp[1];
        for (int j = 0; j < Hn; j++) { float v = ao[j]; l0 += v * Wf[j * 2]; l1 += v * Wf[j * 2 + 1]; }
        l0 = l0 > 0.f ? l0 : __expf(l0) - 1.f;
        l1 = l1 > 0.f ? l1 : __expf(l1) - 1.f;
        l0 += out1[sq * 2]; l1 += out1[sq * 2 + 1];
        float m = fmaxf(l0, l1);
        float e0 = __expf(l0 - m), e1 = __expf(l1 - m);
        float inv = 1.f / (e0 + e1);
        dout[1 + sq * 2] = e0 * inv;
        dout[2 + sq * 2] = e1 * inv;
    }
}

__global__ __launch_bounds__(512) void loss_k(float* __restrict__ dout,
                                              const int* __restrict__ label)
{
    __shared__ float red[512];
    const int tid = threadIdx.x;
    float a = 0.f;
    if (tid < Sn) {
        float p0 = dout[1 + 2 * tid], p1 = dout[2 + 2 * tid];
        float m = fmaxf(p0, p1);
        float lse = m + __logf(__expf(p0 - m) + __expf(p1 - m));
        float pl = label[tid] ? p1 : p0;
        a = -(pl - lse);
    }
    red[tid] = a;
    __syncthreads();
    for (int o = 256; o; o >>= 1) {
        if (tid < o) red[tid] += red[tid + o];
        __syncthreads();
    }
    if (tid == 0) dout[0] = red[0] / (float)Sn;
}

extern "C" void kernel_launch(void* const* d_in, const int* in_sizes, int n_in,
                              void* d_out, int out_size, void* d_ws, size_t ws_size,
                              hipStream_t stream)
{
    const float* text  = (const float*)d_in[0];
    const float* price = (const float*)d_in[1];
    const int*   label = (const int*)  d_in[2];
    const float* Wih_p = (const float*)d_in[5];
    const float* Whh_p = (const float*)d_in[6];
    const float* bih_p = (const float*)d_in[7];
    const float* bhh_p = (const float*)d_in[8];
    const float* Wa_p  = (const float*)d_in[9];
    const float* va_p  = (const float*)d_in[10];
    const float* Wih_t = (const float*)d_in[11];
    const float* Whh_t = (const float*)d_in[12];
    const float* bih_t = (const float*)d_in[13];
    const float* bhh_t = (const float*)d_in[14];
    const float* Wa_t  = (const float*)d_in[15];
    const float* va_t  = (const float*)d_in[16];
    const float* Wih_s = (const float*)d_in[17];
    const float* Whh_s = (const float*)d_in[18];
    const float* bih_s = (const float*)d_in[19];
    const float* bhh_s = (const float*)d_in[20];
    const float* Wa_s  = (const float*)d_in[21];
    const float* va_s  = (const float*)d_in[22];
    const float* Wb    = (const float*)d_in[23];
    const float* bb    = (const float*)d_in[24];
    const float* Wbl   = (const float*)d_in[25];
    const float* bbl   = (const float*)d_in[26];
    const float* Wq    = (const float*)d_in[27];
    const float* bq    = (const float*)d_in[28];
    const float* Wk    = (const float*)d_in[29];
    const float* bk    = (const float*)d_in[30];
    const float* Wf    = (const float*)d_in[31];
    const float* bf_   = (const float*)d_in[32];

    float* ws = (float*)d_ws;
    float* news     = ws;              // 320000
    float* xprice   = ws + 320000;     // 32000
    float* combined = ws + 384000;     // 32000
    float* qg       = ws + 416000;     // 32000
    float* kg       = ws + 448000;     // 32000
    float* out1     = ws + 480000;     // 1000
    float* u        = ws + 481000;     // 2,048,000 (8.2 MB)
    float* gi2      = ws + 2529000;    // 38,400,000 (153.6 MB)
    float* dout = (float*)d_out;

    price_gru<<<Sn, 64, 0, stream>>>(price, Wih_p, Whh_p, bih_p, bhh_p, Wa_p, va_p, xprice);
    k1_mega<<<4500, 256, 0, stream>>>(text, Wih_t, bih_t, gi2, Wb, xprice, u);
    gru_text_f<<<Sn, 64, 0, stream>>>(gi2, Whh_t, bhh_t, Wa_t, va_t, news);
    day_finish<<<Sn, 64, 0, stream>>>(news,
                                      Wih_s, Whh_s, bih_s, bhh_s, Wa_s, va_s,
                                      u, bb, Wq, bq, Wk, bk, Wbl, bbl,
                                      combined, qg, kg, out1);
    mhsa<<<Sn, 256, 0, stream>>>(qg, kg, combined, Wf, bf_, out1, dout);
    loss_k<<<1, 512, 0, stream>>>(dout, label);
}